// Round 3
// baseline (89.869 us; speedup 1.0000x reference)
//
#include <hip/hip_runtime.h>

#define IMG 28
#define FLATK 784     // 28*28
#define OHW 26
#define FLAT 676      // 26*26
#define HID 100
#define NCLS 10
#define KP 832        // K padded to 13*64
#define BK 64         // k per step
#define NSTEPS 13
#define BM 128        // rows per block
#define ROWB 144      // A-tile row stride in bytes (64 bf16 = 128 B + 16 B pad)
#define BUFSZ 18432   // 128 * 144
typedef __attribute__((ext_vector_type(8))) short bfrag;   // 8 bf16 (4 VGPR)
typedef __attribute__((ext_vector_type(4))) float f32x4;
typedef __attribute__((ext_vector_type(4))) unsigned int u32x4;

__device__ __forceinline__ unsigned short f2bf(float f) {
    unsigned u = __float_as_uint(f);
    u = (u + 0x7fffu + ((u >> 16) & 1u)) >> 16;   // RNE
    return (unsigned short)u;
}

// Kernel 1: fold conv into fc1 -> bf16 W1eff [128 n][832 k] (zero-padded),
// and w2 -> bf16 [16 n][128 k] (zero-padded).
__global__ void build_weights(const float* __restrict__ conv_w,
                              const float* __restrict__ w1,
                              const float* __restrict__ w2,
                              unsigned short* __restrict__ w1b,
                              unsigned short* __restrict__ w2b) {
    int idx = blockIdx.x * blockDim.x + threadIdx.x;
    if (idx < 128 * KP) {
        int n = idx / KP, k = idx - n * KP;
        float val = 0.f;
        if (n < HID && k < FLATK) {
            int qr = k / IMG, qc = k % IMG;
            #pragma unroll
            for (int i = 0; i < 3; ++i) {
                int r = qr - i;
                if (r < 0 || r >= OHW) continue;
                #pragma unroll
                for (int j = 0; j < 3; ++j) {
                    int c = qc - j;
                    if (c < 0 || c >= OHW) continue;
                    val += conv_w[i * 3 + j] * w1[n * FLAT + r * OHW + c];
                }
            }
        }
        w1b[idx] = f2bf(val);
    } else {
        int t = idx - 128 * KP;
        if (t < 16 * 128) {
            int n = t >> 7, k = t & 127;
            float v = (n < NCLS && k < HID) ? w2[n * HID + k] : 0.f;
            w2b[t] = f2bf(v);
        }
    }
}

// Kernel 2: fused x->conv+fc1(relu)->fc2 via bf16 MFMA.
// 256 threads = 4 waves, 128 rows per block. Reg-staged x with stage-time
// bf16 conversion (v_cvt_pk_bf16_f32), padded LDS A tile, depth-2 pipeline.
__global__ __launch_bounds__(256) void fused_fwd(
    const float* __restrict__ x,              // [65536][784] f32
    const unsigned short* __restrict__ w1b,   // [128][832] bf16
    const float* __restrict__ b1,             // [100]
    const unsigned short* __restrict__ w2b,   // [16][128] bf16
    const float* __restrict__ b2,             // [10]
    float* __restrict__ out)                  // [65536][10] f32
{
    // 2 x bf16 A tile [128][72] (144 B rows) = 36864 B; h1 aliased after.
    __shared__ char smem[2 * BUFSZ] __attribute__((aligned(128)));

    const int tid  = threadIdx.x;
    const int lane = tid & 63;
    const int wv   = tid >> 6;
    const int row0 = blockIdx.x * BM;

    f32x4 acc[2][8];
    #pragma unroll
    for (int m = 0; m < 2; ++m)
        #pragma unroll
        for (int n = 0; n < 8; ++n)
            acc[m][n] = f32x4{0.f, 0.f, 0.f, 0.f};

    // per-lane stage geometry: 4 chunks, chunk i = row (lane>>3)+8i of the
    // wave's 32-row slab, 8 f32 at col (lane&7)*8 .. +8
    const int srow = (wv << 5) + (lane >> 3);
    const int scol = (lane & 7) << 3;

    f32x4 rA[8], rB[8];

    auto loadregs = [&](f32x4 (&r)[8], int s) {
        int k = s * BK + scol;
        if (k >= FLATK) k -= FLATK;   // pad region: wrapped finite garbage, B rows are 0
        #pragma unroll
        for (int i = 0; i < 4; ++i) {
            const float* g = x + (size_t)(row0 + srow + (i << 3)) * FLATK + k;
            r[2 * i]     = *(const f32x4*)g;
            r[2 * i + 1] = *(const f32x4*)(g + 4);
        }
    };

    auto cvtwrite = [&](f32x4 (&r)[8], unsigned bufoff) {
        #pragma unroll
        for (int i = 0; i < 4; ++i) {
            unsigned addr = bufoff + (unsigned)(srow + (i << 3)) * ROWB + ((lane & 7) << 4);
            u32x4 w;
            asm("v_cvt_pk_bf16_f32 %0, %1, %2" : "=v"(w.x) : "v"(r[2*i].x),   "v"(r[2*i].y));
            asm("v_cvt_pk_bf16_f32 %0, %1, %2" : "=v"(w.y) : "v"(r[2*i].z),   "v"(r[2*i].w));
            asm("v_cvt_pk_bf16_f32 %0, %1, %2" : "=v"(w.z) : "v"(r[2*i+1].x), "v"(r[2*i+1].y));
            asm("v_cvt_pk_bf16_f32 %0, %1, %2" : "=v"(w.w) : "v"(r[2*i+1].z), "v"(r[2*i+1].w));
            *(u32x4*)(smem + addr) = w;
        }
    };

    auto compute = [&](int s, unsigned bufoff) {
        const int k0 = s * BK;
        #pragma unroll
        for (int kc = 0; kc < 2; ++kc) {
            const unsigned cb = (unsigned)(kc << 6) + ((lane >> 4) << 4);
            bfrag a0 = *(const bfrag*)(smem + bufoff + (unsigned)((wv << 5) + (lane & 15)) * ROWB + cb);
            bfrag a1 = *(const bfrag*)(smem + bufoff + (unsigned)((wv << 5) + 16 + (lane & 15)) * ROWB + cb);
            #pragma unroll
            for (int nt = 0; nt < 8; ++nt) {
                const bfrag bw = *(const bfrag*)(w1b + (size_t)((nt << 4) + (lane & 15)) * KP
                                                 + k0 + (kc << 5) + ((lane >> 4) << 3));
                acc[0][nt] = __builtin_amdgcn_mfma_f32_16x16x32_bf16(a0, bw, acc[0][nt], 0, 0, 0);
                acc[1][nt] = __builtin_amdgcn_mfma_f32_16x16x32_bf16(a1, bw, acc[1][nt], 0, 0, 0);
            }
        }
    };

    loadregs(rA, 0);
    #pragma unroll 1
    for (int s = 0; s < NSTEPS - 1; s += 2) {
        loadregs(rB, s + 1);          // in flight across cvt+compute of step s
        cvtwrite(rA, 0u);             // compiler waits only on rA's loads
        __syncthreads();
        compute(s, 0u);
        if (s + 2 < NSTEPS) loadregs(rA, s + 2);
        cvtwrite(rB, BUFSZ);
        __syncthreads();
        compute(s + 1, BUFSZ);
    }
    // final step (s = 12, even): rA was loaded at s=10's prefetch
    cvtwrite(rA, 0u);
    __syncthreads();
    compute(NSTEPS - 1, 0u);
    __syncthreads();   // all A reads done before aliasing smem with h1

    // epilogue 1: bias + relu -> bf16 h1 in LDS [128][136]
    unsigned short (*H1)[136] = (unsigned short (*)[136])smem;
    #pragma unroll
    for (int nt = 0; nt < 8; ++nt) {
        int col = (nt << 4) + (lane & 15);
        float bias = (col < HID) ? b1[col] : 0.f;
        #pragma unroll
        for (int mf = 0; mf < 2; ++mf) {
            int rbase = (wv << 5) + (mf << 4) + ((lane >> 4) << 2);
            #pragma unroll
            for (int q = 0; q < 4; ++q) {
                float v = acc[mf][nt][q] + bias;
                H1[rbase + q][col] = f2bf(fmaxf(v, 0.f));
            }
        }
    }
    __syncthreads();

    // layer 2: [128 rows] x [16 cols] over K=128 (pad cols/k are exact zeros)
    f32x4 acc2[2] = {f32x4{0.f,0.f,0.f,0.f}, f32x4{0.f,0.f,0.f,0.f}};
    #pragma unroll
    for (int ks = 0; ks < 4; ++ks) {
        const bfrag bw = *(const bfrag*)(w2b + (lane & 15) * 128 + (ks << 5) + ((lane >> 4) << 3));
        #pragma unroll
        for (int mf = 0; mf < 2; ++mf) {
            int r = (wv << 5) + (mf << 4) + (lane & 15);
            const bfrag ah = *(const bfrag*)&H1[r][(ks << 5) + ((lane >> 4) << 3)];
            acc2[mf] = __builtin_amdgcn_mfma_f32_16x16x32_bf16(ah, bw, acc2[mf], 0, 0, 0);
        }
    }

    int col = lane & 15;
    if (col < NCLS) {
        float bias2 = b2[col];
        #pragma unroll
        for (int mf = 0; mf < 2; ++mf) {
            int rbase = row0 + (wv << 5) + (mf << 4) + ((lane >> 4) << 2);
            #pragma unroll
            for (int q = 0; q < 4; ++q)
                out[(size_t)(rbase + q) * NCLS + col] = acc2[mf][q] + bias2;
        }
    }
}

extern "C" void kernel_launch(void* const* d_in, const int* in_sizes, int n_in,
                              void* d_out, int out_size, void* d_ws, size_t ws_size,
                              hipStream_t stream) {
    const float* x      = (const float*)d_in[0];
    const float* conv_w = (const float*)d_in[1];
    const float* w1     = (const float*)d_in[2];
    const float* b1     = (const float*)d_in[3];
    const float* w2     = (const float*)d_in[4];
    const float* b2     = (const float*)d_in[5];
    float* out = (float*)d_out;

    unsigned short* w1b = (unsigned short*)d_ws;   // 128*832*2 = 208 KB
    unsigned short* w2b = w1b + 128 * KP;          // 16*128*2  = 4 KB

    build_weights<<<(128 * KP + 16 * 128 + 255) / 256, 256, 0, stream>>>(conv_w, w1, w2, w1b, w2b);
    fused_fwd<<<65536 / BM, 256, 0, stream>>>(x, w1b, b1, w2b, b2, out);
}